// Round 1
// 423.892 us; speedup vs baseline: 1.0032x; 1.0032x over previous
//
#include <hip/hip_runtime.h>
#include <hip/hip_bf16.h>
#include <cstdint>

// Set2Set forward, 3 steps. N=200000, B=1024 segments, D=256. All f32 I/O.
// Round 7: attention streaming loop rebuilt for BW saturation:
//   - 4-row groups per wave (amortizes the 6-level shfl_xor chain 4x,
//     one online-softmax update per 4 rows)
//   - 3-buffer, 2-groups-ahead prefetch (up to 12 KB in flight per wave
//     vs 1 KB before; ~190 KB/CU >> ~9 KB needed for 6.3 TB/s)
// GEMM (K=512 collapsed, XOR-swizzled LDS W staging, bf16 hi/lo
// compensated 3-mfma) and prep unchanged from round 6.

#define NN     200000
#define BSEG   1024
#define DD     256
#define KA     512     // collapsed K
#define FOURD  1024

using bf16x8 = __attribute__((ext_vector_type(8))) __bf16;
using f32x4  = __attribute__((ext_vector_type(4))) float;

__device__ __forceinline__ float bf2f(unsigned int u) {
  union { unsigned int i; float f; } v; v.i = (u & 0xffffu) << 16; return v.f;
}
__device__ __forceinline__ unsigned short f2bf(float f) {
  union { float f; unsigned int i; } v; v.f = f;
  unsigned int x = v.i;
  if ((x & 0x7fffffffu) > 0x7f800000u) return (unsigned short)((x >> 16) | 0x40);
  return (unsigned short)((x + 0x7fffu + ((x >> 16) & 1u)) >> 16);
}
__device__ __forceinline__ void split_bf(float f, unsigned short& hi, unsigned short& lo) {
  hi = f2bf(f);
  lo = f2bf(f - bf2f(hi));
}

// ---- combined prep: seg bounds + W1/W2 split + A init + c=0 --------------
__global__ void prep_all(const int* __restrict__ batch, int* __restrict__ segs,
                         const float* __restrict__ Wih, const float* __restrict__ Whh,
                         const float* __restrict__ bih, const float* __restrict__ bhh,
                         unsigned short* __restrict__ W1hi, unsigned short* __restrict__ W1lo,
                         unsigned short* __restrict__ W2hi, unsigned short* __restrict__ W2lo,
                         float* __restrict__ bias,
                         const float* __restrict__ qst,
                         unsigned short* __restrict__ Ahi, unsigned short* __restrict__ Alo,
                         float* __restrict__ c) {
  int idx = blockIdx.x * 256 + threadIdx.x;       // grid covers 524288
  if (idx <= BSEG) {
    int lo = 0, hi = NN;
    while (lo < hi) { int mid = (lo + hi) >> 1; if (batch[mid] < idx) lo = mid + 1; else hi = mid; }
    segs[idx] = lo;
  }
  if (idx < FOURD) bias[idx] = bih[idx] + bhh[idx];
  if (idx < FOURD * KA) {
    int j = idx / KA, k = idx - j * KA;
    float w1 = Wih[j * 512 + k];
    float w2 = (k < 256) ? (Wih[j * 512 + k] + Whh[j * 256 + k])
                         : Wih[j * 512 + k];
    unsigned short hi, lo;
    split_bf(w1, hi, lo); W1hi[idx] = hi; W1lo[idx] = lo;
    split_bf(w2, hi, lo); W2hi[idx] = hi; W2lo[idx] = lo;
  }
  if (idx < BSEG * KA) {
    unsigned short hi, lo; split_bf(qst[idx], hi, lo);
    Ahi[idx] = hi; Alo[idx] = lo;
  }
  if (idx < BSEG * DD) c[idx] = 0.f;
}

// ---- LSTM gates GEMM: gates = (Ahi+Alo) @ (Whi+Wlo)^T, K=512 -------------
// 256 blocks, each 128 rows x 32 cols. W chunk (32 x 64k, hi+lo) staged in
// LDS with XOR swizzle (row stride 64 elems = 32 banks; col-block ^= row&7
// -> conflict-free b128 reads & writes). A read direct from global.
__global__ __launch_bounds__(256) void gemm_gates(const unsigned short* __restrict__ Ahi,
                                                  const unsigned short* __restrict__ Alo,
                                                  const unsigned short* __restrict__ Whi,
                                                  const unsigned short* __restrict__ Wlo,
                                                  float* __restrict__ gates) {
  int bx = blockIdx.x;
  int m0 = (bx >> 5) << 7;      // * 128
  int n0 = (bx & 31) << 5;      // * 32
  int t = threadIdx.x, w = t >> 6, lane = t & 63;
  int r16 = lane & 15, quad = lane >> 4;

  __shared__ unsigned short sWhi[32 * 64];
  __shared__ unsigned short sWlo[32 * 64];

  f32x4 acc[2][2] = {};

  const unsigned short* a0h = Ahi + (size_t)(m0 + 32 * w + r16) * KA + quad * 8;
  const unsigned short* a0l = Alo + (size_t)(m0 + 32 * w + r16) * KA + quad * 8;

  int srow = t >> 3;            // 0..31
  int scb  = t & 7;             // 0..7 col-block (8 bf16 each)
  const unsigned short* gwh = Whi + (size_t)(n0 + srow) * KA + scb * 8;
  const unsigned short* gwl = Wlo + (size_t)(n0 + srow) * KA + scb * 8;
  int sdst = srow * 64 + ((scb ^ (srow & 7)) * 8);

  for (int kc = 0; kc < KA; kc += 64) {
    __syncthreads();
    *(bf16x8*)&sWhi[sdst] = *(const bf16x8*)(gwh + kc);
    *(bf16x8*)&sWlo[sdst] = *(const bf16x8*)(gwl + kc);
    __syncthreads();
    #pragma unroll
    for (int ks = 0; ks < 2; ++ks) {
      bf16x8 bh[2], bl[2];
      #pragma unroll
      for (int ni = 0; ni < 2; ++ni) {
        int wr = 16 * ni + r16;
        int off = wr * 64 + (((ks * 4 + quad) ^ (wr & 7)) * 8);
        bh[ni] = *(const bf16x8*)&sWhi[off];
        bl[ni] = *(const bf16x8*)&sWlo[off];
      }
      #pragma unroll
      for (int ms = 0; ms < 2; ++ms) {
        bf16x8 a  = *(const bf16x8*)(a0h + (size_t)ms * 16 * KA + kc + ks * 32);
        bf16x8 al = *(const bf16x8*)(a0l + (size_t)ms * 16 * KA + kc + ks * 32);
        #pragma unroll
        for (int ni = 0; ni < 2; ++ni) {
          acc[ms][ni] = __builtin_amdgcn_mfma_f32_16x16x32_bf16(a,  bh[ni], acc[ms][ni], 0, 0, 0);
          acc[ms][ni] = __builtin_amdgcn_mfma_f32_16x16x32_bf16(a,  bl[ni], acc[ms][ni], 0, 0, 0);
          acc[ms][ni] = __builtin_amdgcn_mfma_f32_16x16x32_bf16(al, bh[ni], acc[ms][ni], 0, 0, 0);
        }
      }
    }
  }
  #pragma unroll
  for (int ms = 0; ms < 2; ++ms)
    #pragma unroll
    for (int ni = 0; ni < 2; ++ni)
      #pragma unroll
      for (int r = 0; r < 4; ++r)
        gates[(size_t)(m0 + 32 * w + 16 * ms + quad * 4 + r) * FOURD
              + n0 + 16 * ni + r16] = acc[ms][ni][r];
}

// ---- fused LSTM-pointwise + one-pass online-softmax attention ------------
// Block b: compute h_b from gates row b, keep in LDS, then stream segment
// b's x rows once. Each wave processes 4-row groups (stride 16 across the
// 4 waves) with a 3-buffer 2-ahead prefetch pipeline; per-wave online
// softmax state merged at the end. A (next GEMM input) = [h | r].

// Load a 4-row group starting at `base` (addresses clamped to tend-1;
// clamped rows are masked to weight 0 in PROC). Requires base < tend.
#define LDG(buf, base) do {                                                 \
    int r0_ = (base);                                                       \
    int r1_ = (base) + 1 < tend ? (base) + 1 : tend - 1;                    \
    int r2_ = (base) + 2 < tend ? (base) + 2 : tend - 1;                    \
    int r3_ = (base) + 3 < tend ? (base) + 3 : tend - 1;                    \
    buf[0] = *(const float4*)(x + (size_t)r0_ * DD + lane * 4);             \
    buf[1] = *(const float4*)(x + (size_t)r1_ * DD + lane * 4);             \
    buf[2] = *(const float4*)(x + (size_t)r2_ * DD + lane * 4);             \
    buf[3] = *(const float4*)(x + (size_t)r3_ * DD + lane * 4);             \
  } while (0)

// Process a 4-row group: 4 interleaved butterfly reductions, one online
// softmax update for the group. OOB rows get d=-3.4e38 -> weight exactly 0.
#define PROC(buf, base) do {                                                \
    float dx_ = buf[0].x*q.x + buf[0].y*q.y + buf[0].z*q.z + buf[0].w*q.w;  \
    float dy_ = buf[1].x*q.x + buf[1].y*q.y + buf[1].z*q.z + buf[1].w*q.w;  \
    float dz_ = buf[2].x*q.x + buf[2].y*q.y + buf[2].z*q.z + buf[2].w*q.w;  \
    float dw_ = buf[3].x*q.x + buf[3].y*q.y + buf[3].z*q.z + buf[3].w*q.w;  \
    _Pragma("unroll")                                                       \
    for (int off_ = 32; off_; off_ >>= 1) {                                 \
      dx_ += __shfl_xor(dx_, off_);                                         \
      dy_ += __shfl_xor(dy_, off_);                                         \
      dz_ += __shfl_xor(dz_, off_);                                         \
      dw_ += __shfl_xor(dw_, off_);                                         \
    }                                                                       \
    if ((base) + 1 >= tend) dy_ = -3.402823466e38f;                         \
    if ((base) + 2 >= tend) dz_ = -3.402823466e38f;                         \
    if ((base) + 3 >= tend) dw_ = -3.402823466e38f;                         \
    float mn_ = fmaxf(fmaxf(fmaxf(dx_, dy_), fmaxf(dz_, dw_)), m);          \
    float al_ = __expf(m - mn_);                                            \
    float w0_ = __expf(dx_ - mn_), w1_ = __expf(dy_ - mn_);                 \
    float w2_ = __expf(dz_ - mn_), w3_ = __expf(dw_ - mn_);                 \
    l = l * al_ + (w0_ + w1_) + (w2_ + w3_);                                \
    v.x = (v.x*al_ + w0_*buf[0].x) + (w1_*buf[1].x + w2_*buf[2].x) + w3_*buf[3].x; \
    v.y = (v.y*al_ + w0_*buf[0].y) + (w1_*buf[1].y + w2_*buf[2].y) + w3_*buf[3].y; \
    v.z = (v.z*al_ + w0_*buf[0].z) + (w1_*buf[1].z + w2_*buf[2].z) + w3_*buf[3].z; \
    v.w = (v.w*al_ + w0_*buf[0].w) + (w1_*buf[1].w + w2_*buf[2].w) + w3_*buf[3].w; \
    m = mn_;                                                                \
  } while (0)

__global__ __launch_bounds__(256) void attn_fused(const float* __restrict__ x,
                                                  const int* __restrict__ segs,
                                                  const float* __restrict__ gates,
                                                  const float* __restrict__ bias,
                                                  float* __restrict__ c,
                                                  unsigned short* __restrict__ Ahi,
                                                  unsigned short* __restrict__ Alo,
                                                  float* __restrict__ qout) {
  int b = blockIdx.x, t = threadIdx.x;
  int w = t >> 6, lane = t & 63;

  // --- LSTM pointwise, channel t of row b (gate order i,f,g,o) ---
  const float* g = gates + (size_t)b * FOURD;
  float gi = g[t]       + bias[t];
  float gf = g[256 + t] + bias[256 + t];
  float gg = g[512 + t] + bias[512 + t];
  float go = g[768 + t] + bias[768 + t];
  float ig = 1.f / (1.f + expf(-gi));
  float fg = 1.f / (1.f + expf(-gf));
  float gt = tanhf(gg);
  float og = 1.f / (1.f + expf(-go));
  int cidx = b * DD + t;
  float cn = fg * c[cidx] + ig * gt;
  c[cidx] = cn;
  float hn = og * tanhf(cn);

  __shared__ __align__(16) float sh[DD];
  sh[t] = hn;
  {
    unsigned short hi, lo; split_bf(hn, hi, lo);
    size_t ro = (size_t)b * KA;
    Ahi[ro + t] = hi;  Alo[ro + t] = lo;             // h-part [0,256)
    qout[(size_t)b * 512 + t] = hn;                  // output q half
  }
  __syncthreads();

  // --- attention over segment b ---
  int s = segs[b], tend = segs[b + 1];
  float4 q = *(const float4*)(sh + lane * 4);

  float m = -3.402823466e38f;
  float l = 0.f;
  float4 v = {0.f, 0.f, 0.f, 0.f};

  // wave w owns 4-row groups at rows s + w*4 + k*16; 3 buffers, 2 ahead.
  int i0 = s + w * 4;
  float4 b0[4], b1[4], b2[4];
  if (i0      < tend) LDG(b0, i0);
  if (i0 + 16 < tend) LDG(b1, i0 + 16);
  if (i0 + 32 < tend) LDG(b2, i0 + 32);
  for (int i = i0; i < tend; i += 48) {
    PROC(b0, i);
    if (i + 48 < tend) LDG(b0, i + 48);
    if (i + 16 < tend) {
      PROC(b1, i + 16);
      if (i + 64 < tend) LDG(b1, i + 64);
      if (i + 32 < tend) {
        PROC(b2, i + 32);
        if (i + 80 < tend) LDG(b2, i + 80);
      }
    }
  }

  __shared__ float sm[4], sl[4];
  __shared__ __align__(16) float sv[4][DD];
  if (lane == 0) { sm[w] = m; sl[w] = l; }
  *(float4*)(&sv[w][lane * 4]) = v;
  __syncthreads();

  float M = fmaxf(fmaxf(sm[0], sm[1]), fmaxf(sm[2], sm[3]));
  if (M < -1e37f) M = 0.f;             // mirror reference isfinite guard
  float a0 = __expf(sm[0] - M), a1 = __expf(sm[1] - M);
  float a2 = __expf(sm[2] - M), a3 = __expf(sm[3] - M);
  float L = sl[0] * a0 + sl[1] * a1 + sl[2] * a2 + sl[3] * a3;
  float r = (sv[0][t] * a0 + sv[1][t] * a1 + sv[2][t] * a2 + sv[3][t] * a3)
            / (L + 1e-16f);

  unsigned short hi, lo; split_bf(r, hi, lo);
  size_t ro = (size_t)b * KA;
  Ahi[ro + DD + t] = hi;  Alo[ro + DD + t] = lo;    // r-part [256,512)
  qout[(size_t)b * 512 + DD + t] = r;               // output r half
}

// ---- launch --------------------------------------------------------------
extern "C" void kernel_launch(void* const* d_in, const int* in_sizes, int n_in,
                              void* d_out, int out_size, void* d_ws, size_t ws_size,
                              hipStream_t stream) {
  const float* x    = (const float*)d_in[0];
  const int*   batc = (const int*)d_in[2];
  const float* qst  = (const float*)d_in[3];
  const float* Wih  = (const float*)d_in[4];
  const float* Whh  = (const float*)d_in[5];
  const float* bih  = (const float*)d_in[6];
  const float* bhh  = (const float*)d_in[7];
  float* out = (float*)d_out;

  char* ws = (char*)d_ws;
  size_t off = 0;
  auto alloc = [&](size_t bytes) -> void* {
    void* p = ws + off; off = (off + bytes + 255) & ~(size_t)255; return p;
  };
  int*            segs = (int*)alloc((size_t)(BSEG + 1) * 4);
  unsigned short* W1hi = (unsigned short*)alloc((size_t)FOURD * KA * 2);
  unsigned short* W1lo = (unsigned short*)alloc((size_t)FOURD * KA * 2);
  unsigned short* W2hi = (unsigned short*)alloc((size_t)FOURD * KA * 2);
  unsigned short* W2lo = (unsigned short*)alloc((size_t)FOURD * KA * 2);
  unsigned short* Ahi  = (unsigned short*)alloc((size_t)BSEG * KA * 2);
  unsigned short* Alo  = (unsigned short*)alloc((size_t)BSEG * KA * 2);
  float*          gate = (float*)alloc((size_t)BSEG * FOURD * 4);
  float*          c    = (float*)alloc((size_t)BSEG * DD * 4);
  float*          bias = (float*)alloc((size_t)FOURD * 4);

  prep_all<<<(FOURD * KA + 255) / 256, 256, 0, stream>>>(
      batc, segs, Wih, Whh, bih, bhh, W1hi, W1lo, W2hi, W2lo, bias, qst, Ahi, Alo, c);

  for (int step = 0; step < 3; ++step) {
    const unsigned short* whi = step ? W2hi : W1hi;
    const unsigned short* wlo = step ? W2lo : W1lo;
    gemm_gates<<<256, 256, 0, stream>>>(Ahi, Alo, whi, wlo, gate);
    attn_fused<<<BSEG, 256, 0, stream>>>(x, segs, gate, bias, c, Ahi, Alo, out);
  }
}